// Round 2
// baseline (1586.766 us; speedup 1.0000x reference)
//
#include <hip/hip_runtime.h>

#define NN 50000
#define NE 1600000
#define DD 64
#define NB 64            // nodes per bucket
#define NBKT 782         // ceil(NN/NB)
#define NSHARD 8         // blockIdx%8 ~ XCD id -> same-L2 sequential appends
#define BCAP 384         // per (bucket,shard) capacity: mean 256, sigma 16 -> +8 sigma
#define WS_STRIDE 68     // 128x68 fp32 LDS for W^T in GEMM

static __device__ __forceinline__ unsigned short f2bf(float f) {
    unsigned int u = __float_as_uint(f);
    unsigned int r = (u + 0x7FFFu + ((u >> 16) & 1u)) >> 16;   // RNE
    return (unsigned short)r;
}
static __device__ __forceinline__ float bf2f(unsigned short h) {
    return __uint_as_float((unsigned int)h << 16);
}

// ---------------------------------------------------------------------------
// x (fp32) -> xb (bf16), float4 reads / ushort4 writes.
// ---------------------------------------------------------------------------
__global__ __launch_bounds__(256) void cast_bf16(
    const float* __restrict__ in, ushort* __restrict__ out, int n4)
{
    int i = blockIdx.x * 256 + threadIdx.x;
    if (i >= n4) return;
    float4 v = ((const float4*)in)[i];
    ushort4 o;
    o.x = f2bf(v.x); o.y = f2bf(v.y); o.z = f2bf(v.z); o.w = f2bf(v.w);
    ((ushort4*)out)[i] = o;
}

// ---------------------------------------------------------------------------
// Bin edges into (bucket, shard) sub-buffers. shard = blockIdx%8 keeps each
// sub-buffer's cursor-sequential 8B appends inside ONE XCD's L2 -> full-line
// evictions (kills the 102MB write-allocate of the old random-target ELL).
// Record: word0 = dst | (s_local<<16)  (dst<65536, s_local<64), word1 = w.
// ---------------------------------------------------------------------------
__global__ __launch_bounds__(256) void scatter_buckets(
    const int* __restrict__ ei, const float* __restrict__ ew,
    int* __restrict__ bcnt, int2* __restrict__ bbuf)
{
    int e = blockIdx.x * 256 + threadIdx.x;   // grid = NE/256 exactly
    int s = ei[e];           // edge_index[0] = src (scatter target)
    int d = ei[NE + e];      // edge_index[1] = dst (gather source)
    float w = ew[e];
    int slot = (s >> 6) * NSHARD + (blockIdx.x & 7);
    int pos = atomicAdd(&bcnt[slot], 1);
    if (pos < BCAP)
        bbuf[(size_t)slot * BCAP + pos] = make_int2(d | ((s & 63) << 16), __float_as_int(w));
}

// ---------------------------------------------------------------------------
// Scatter-mean per bucket: block = 8 waves, wave w drains shard w.
// LDS acc[64 nodes][64 feats] fp32 (16KB); lane = feature. Neighbor rows are
// bf16 (128B coalesced wave gather). LDS float atomics: acc addresses are
// lane-linear -> 2-way bank aliasing (free); cross-wave same-row collisions
// are rare (64 rows, 8 waves).
// ---------------------------------------------------------------------------
__global__ __launch_bounds__(512) void aggregate_buckets(
    const ushort* __restrict__ feat, const int* __restrict__ bcnt,
    const int2* __restrict__ bbuf, float* __restrict__ agg)
{
    __shared__ float acc[NB * DD];   // 16 KB
    __shared__ float cnt[NB];
    int tid = threadIdx.x;
    int bkt = blockIdx.x;

    for (int i = tid; i < NB * DD; i += 512) acc[i] = 0.f;
    if (tid < NB) cnt[tid] = 0.f;
    __syncthreads();

    int wave = tid >> 6, lane = tid & 63;
    int slot = bkt * NSHARD + wave;
    int n = bcnt[slot]; if (n > BCAP) n = BCAP;
    const int2* __restrict__ rec = bbuf + (size_t)slot * BCAP;

    int i = 0;
    for (; i + 4 <= n; i += 4) {
        int2 r0 = rec[i + 0];
        int2 r1 = rec[i + 1];
        int2 r2 = rec[i + 2];
        int2 r3 = rec[i + 3];
        float v0 = bf2f(feat[(r0.x & 0xFFFF) * DD + lane]);
        float v1 = bf2f(feat[(r1.x & 0xFFFF) * DD + lane]);
        float v2 = bf2f(feat[(r2.x & 0xFFFF) * DD + lane]);
        float v3 = bf2f(feat[(r3.x & 0xFFFF) * DD + lane]);
        atomicAdd(&acc[((r0.x >> 16) & 63) * DD + lane], __int_as_float(r0.y) * v0);
        atomicAdd(&acc[((r1.x >> 16) & 63) * DD + lane], __int_as_float(r1.y) * v1);
        atomicAdd(&acc[((r2.x >> 16) & 63) * DD + lane], __int_as_float(r2.y) * v2);
        atomicAdd(&acc[((r3.x >> 16) & 63) * DD + lane], __int_as_float(r3.y) * v3);
        if (lane == 0) {
            atomicAdd(&cnt[(r0.x >> 16) & 63], 1.f);
            atomicAdd(&cnt[(r1.x >> 16) & 63], 1.f);
            atomicAdd(&cnt[(r2.x >> 16) & 63], 1.f);
            atomicAdd(&cnt[(r3.x >> 16) & 63], 1.f);
        }
    }
    for (; i < n; ++i) {
        int2 r = rec[i];
        float v = bf2f(feat[(r.x & 0xFFFF) * DD + lane]);
        atomicAdd(&acc[((r.x >> 16) & 63) * DD + lane], __int_as_float(r.y) * v);
        if (lane == 0) atomicAdd(&cnt[(r.x >> 16) & 63], 1.f);
    }
    __syncthreads();

    for (int idx = tid; idx < NB * DD; idx += 512) {
        int sl = idx >> 6;
        int node = bkt * NB + sl;
        if (node < NN)
            agg[(size_t)node * DD + (idx & 63)] = acc[idx] / fmaxf(cnt[sl], 1.f);
    }
}

// ---------------------------------------------------------------------------
// out[n][j] = relu( b[j] + X[n][:]·W[j][0:64] + A[n][:]·W[j][64:128] )
// Block = 64 nodes; W^T in LDS; 4x4 micro-tile per thread. Optionally also
// emits a bf16 copy (outb) for the next layer's gather.
// ---------------------------------------------------------------------------
__global__ __launch_bounds__(256) void sage_gemm_relu(
    const float* __restrict__ X, const float* __restrict__ A,
    const float* __restrict__ W, const float* __restrict__ bias,
    float* __restrict__ out, ushort* __restrict__ outb)
{
    __shared__ float Ws[128 * WS_STRIDE];
    int tid = threadIdx.x;
    int nb = blockIdx.x * 64;

    for (int idx = tid; idx < 8192; idx += 256) {
        int j = idx >> 7;
        int k = idx & 127;
        Ws[k * WS_STRIDE + j] = W[idx];
    }
    __syncthreads();

    int tx = tid & 15;
    int ty = tid >> 4;

    int r[4];
#pragma unroll
    for (int i = 0; i < 4; ++i) {
        int row = nb + ty * 4 + i;
        r[i] = row < NN ? row : NN - 1;
    }

    float acc[4][4];
#pragma unroll
    for (int i = 0; i < 4; ++i)
#pragma unroll
        for (int j = 0; j < 4; ++j) acc[i][j] = 0.f;

#pragma unroll 4
    for (int k4 = 0; k4 < 16; ++k4) {
        float4 a[4], w[4];
#pragma unroll
        for (int i = 0; i < 4; ++i)
            a[i] = *(const float4*)&X[r[i] * 64 + k4 * 4];
#pragma unroll
        for (int kk = 0; kk < 4; ++kk)
            w[kk] = *(const float4*)&Ws[(k4 * 4 + kk) * WS_STRIDE + tx * 4];
#pragma unroll
        for (int i = 0; i < 4; ++i) {
            acc[i][0] += a[i].x * w[0].x + a[i].y * w[1].x + a[i].z * w[2].x + a[i].w * w[3].x;
            acc[i][1] += a[i].x * w[0].y + a[i].y * w[1].y + a[i].z * w[2].y + a[i].w * w[3].y;
            acc[i][2] += a[i].x * w[0].z + a[i].y * w[1].z + a[i].z * w[2].z + a[i].w * w[3].z;
            acc[i][3] += a[i].x * w[0].w + a[i].y * w[1].w + a[i].z * w[2].w + a[i].w * w[3].w;
        }
    }
#pragma unroll 4
    for (int k4 = 0; k4 < 16; ++k4) {
        float4 a[4], w[4];
#pragma unroll
        for (int i = 0; i < 4; ++i)
            a[i] = *(const float4*)&A[r[i] * 64 + k4 * 4];
#pragma unroll
        for (int kk = 0; kk < 4; ++kk)
            w[kk] = *(const float4*)&Ws[(64 + k4 * 4 + kk) * WS_STRIDE + tx * 4];
#pragma unroll
        for (int i = 0; i < 4; ++i) {
            acc[i][0] += a[i].x * w[0].x + a[i].y * w[1].x + a[i].z * w[2].x + a[i].w * w[3].x;
            acc[i][1] += a[i].x * w[0].y + a[i].y * w[1].y + a[i].z * w[2].y + a[i].w * w[3].y;
            acc[i][2] += a[i].x * w[0].z + a[i].y * w[1].z + a[i].z * w[2].z + a[i].w * w[3].z;
            acc[i][3] += a[i].x * w[0].w + a[i].y * w[1].w + a[i].z * w[2].w + a[i].w * w[3].w;
        }
    }

    float4 bb = *(const float4*)&bias[tx * 4];
#pragma unroll
    for (int i = 0; i < 4; ++i) {
        int n = nb + ty * 4 + i;
        if (n < NN) {
            float4 o;
            o.x = fmaxf(acc[i][0] + bb.x, 0.f);
            o.y = fmaxf(acc[i][1] + bb.y, 0.f);
            o.z = fmaxf(acc[i][2] + bb.z, 0.f);
            o.w = fmaxf(acc[i][3] + bb.w, 0.f);
            *(float4*)&out[n * 64 + tx * 4] = o;
            if (outb) {
                ushort4 ob;
                ob.x = f2bf(o.x); ob.y = f2bf(o.y); ob.z = f2bf(o.z); ob.w = f2bf(o.w);
                *(ushort4*)&outb[n * 64 + tx * 4] = ob;
            }
        }
    }
}

// ---------------------------------------------------------------------------
extern "C" void kernel_launch(void* const* d_in, const int* in_sizes, int n_in,
                              void* d_out, int out_size, void* d_ws, size_t ws_size,
                              hipStream_t stream)
{
    const float* x  = (const float*)d_in[0];
    const int*   ei = (const int*)d_in[1];
    const float* ew = (const float*)d_in[2];
    const float* W1 = (const float*)d_in[3];
    const float* b1 = (const float*)d_in[4];
    const float* W2 = (const float*)d_in[5];
    const float* b2 = (const float*)d_in[6];
    float* out = (float*)d_out;

    // workspace layout (all 16B-aligned offsets), ~57.65 MB total
    char* ws = (char*)d_ws;
    int*    bcnt = (int*)ws;                         //      25,024 B (pad 32 KB)
    int2*   bbuf = (int2*)(ws + 32768);              //  19,218,432 B (782*8*384*8)
    ushort* xb   = (ushort*)(ws + 19251200);         //   6,400,000 B
    float*  agg  = (float*)(ws + 25651200);          //  12,800,000 B
    float*  h1   = (float*)(ws + 38451200);          //  12,800,000 B
    ushort* h1b  = (ushort*)(ws + 51251200);         //   6,400,000 B

    hipMemsetAsync(bcnt, 0, NBKT * NSHARD * sizeof(int), stream);

    cast_bf16<<<(NN * DD / 4 + 255) / 256, 256, 0, stream>>>(x, xb, NN * DD / 4);
    scatter_buckets<<<NE / 256, 256, 0, stream>>>(ei, ew, bcnt, bbuf);

    // layer 1
    aggregate_buckets<<<NBKT, 512, 0, stream>>>(xb, bcnt, bbuf, agg);
    sage_gemm_relu<<<(NN + 63) / 64, 256, 0, stream>>>(x, agg, W1, b1, h1, h1b);

    // layer 2 (same graph, reuse buckets)
    aggregate_buckets<<<NBKT, 512, 0, stream>>>(h1b, bcnt, bbuf, agg);
    sage_gemm_relu<<<(NN + 63) / 64, 256, 0, stream>>>(h1, agg, W2, b2, out, nullptr);
}

// Round 3
// 402.357 us; speedup vs baseline: 3.9437x; 3.9437x over previous
//
#include <hip/hip_runtime.h>

#define NN 50000
#define NE 1600000
#define DD 64
#define NSH 8            // shards: blockIdx&7 ~ XCD -> one XCD owns each slot line
#define CAP 16           // 16 x 4B records = exactly one 64B line per (node,shard)
#define NSLOT 9          // 8 shards + 1 spill slot per node
#define CSTR 12          // cnt ints per node (8 shard + 1 spill + pad) = 48B, 16B-aligned
#define WS_STRIDE 68     // 128x68 fp32 LDS for W^T in GEMM

static __device__ __forceinline__ unsigned short f2bf(float f) {
    unsigned int u = __float_as_uint(f);
    unsigned int r = (u + 0x7FFFu + ((u >> 16) & 1u)) >> 16;   // RNE
    return (unsigned short)r;
}
static __device__ __forceinline__ float bf2f(unsigned short h) {
    return __uint_as_float((unsigned int)h << 16);
}

// ---------------------------------------------------------------------------
// x (fp32) -> xb (bf16)
// ---------------------------------------------------------------------------
__global__ __launch_bounds__(256) void cast_bf16(
    const float* __restrict__ in, ushort* __restrict__ out, int n4)
{
    int i = blockIdx.x * 256 + threadIdx.x;
    if (i >= n4) return;
    float4 v = ((const float4*)in)[i];
    ushort4 o;
    o.x = f2bf(v.x); o.y = f2bf(v.y); o.z = f2bf(v.z); o.w = f2bf(v.w);
    ((ushort4*)out)[i] = o;
}

// ---------------------------------------------------------------------------
// Bin edges into per-(node,shard) single-line slots. shard = blockIdx&7 ~ XCD
// so every store to a given 64B slot line comes from ONE XCD's L2 -> the line
// fills before eviction (kills Round-1's 102MB write-allocate traffic).
// Record: dst(16b) | w_bf16(16b). Overflow (P~1e-6/slot) spills to slot 8;
// divisor uses raw shard counts = true degree, so spilled edges still count.
// ---------------------------------------------------------------------------
__global__ __launch_bounds__(256) void build_slots(
    const int* __restrict__ ei, const float* __restrict__ ew,
    int* __restrict__ cnt, unsigned int* __restrict__ bbuf)
{
    int e = blockIdx.x * 256 + threadIdx.x;   // grid = NE/256 exactly
    int s = ei[e];           // edge_index[0] = src (scatter target)
    int d = ei[NE + e];      // edge_index[1] = dst (gather source)
    float w = ew[e];
    unsigned int rec = (unsigned int)d | ((unsigned int)f2bf(w) << 16);
    int shard = blockIdx.x & 7;
    int pos = atomicAdd(&cnt[s * CSTR + shard], 1);
    if (pos < CAP) {
        bbuf[(s * NSLOT + shard) * CAP + pos] = rec;
    } else {
        int p2 = atomicAdd(&cnt[s * CSTR + 8], 1);
        if (p2 < CAP) bbuf[(s * NSLOT + 8) * CAP + p2] = rec;
    }
}

// ---------------------------------------------------------------------------
// Scatter-mean as gather: ONE WAVE PER NODE (50K independent waves — the
// Round-2 lesson: never shrink this), lane = feature, register accumulate.
// Records arrive as wave-uniform uint4 (4 recs) -> 4 independent bf16 row
// gathers (128B coalesced each) -> FMA.
// ---------------------------------------------------------------------------
__global__ __launch_bounds__(256) void aggregate(
    const ushort* __restrict__ feat, const int* __restrict__ cnt,
    const unsigned int* __restrict__ bbuf, ushort* __restrict__ aggb)
{
    int node = (blockIdx.x * 256 + threadIdx.x) >> 6;   // grid exact: node < NN
    int lane = threadIdx.x & 63;

    const uint4* cv = (const uint4*)(cnt + node * CSTR);
    uint4 c0 = cv[0];
    uint4 c1 = cv[1];
    unsigned int csp = ((const unsigned int*)(cnt + node * CSTR))[8];
    unsigned int deg = c0.x + c0.y + c0.z + c0.w + c1.x + c1.y + c1.z + c1.w;

    unsigned int ns[NSLOT];
    ns[0] = c0.x; ns[1] = c0.y; ns[2] = c0.z; ns[3] = c0.w;
    ns[4] = c1.x; ns[5] = c1.y; ns[6] = c1.z; ns[7] = c1.w;
    ns[8] = csp;
#pragma unroll
    for (int sl = 0; sl < NSLOT; ++sl) if (ns[sl] > CAP) ns[sl] = CAP;

    const unsigned int* __restrict__ base = bbuf + (size_t)node * NSLOT * CAP;
    float acc = 0.f;

    for (int sl = 0; sl < NSLOT; ++sl) {
        const unsigned int* rp = base + sl * CAP;
        unsigned int n = ns[sl];
        unsigned int i = 0;
        for (; i + 4 <= n; i += 4) {
            uint4 r = *(const uint4*)(rp + i);
            float v0 = bf2f(feat[(r.x & 0xFFFF) * DD + lane]);
            float v1 = bf2f(feat[(r.y & 0xFFFF) * DD + lane]);
            float v2 = bf2f(feat[(r.z & 0xFFFF) * DD + lane]);
            float v3 = bf2f(feat[(r.w & 0xFFFF) * DD + lane]);
            acc += bf2f((unsigned short)(r.x >> 16)) * v0;
            acc += bf2f((unsigned short)(r.y >> 16)) * v1;
            acc += bf2f((unsigned short)(r.z >> 16)) * v2;
            acc += bf2f((unsigned short)(r.w >> 16)) * v3;
        }
        for (; i < n; ++i) {
            unsigned int r = rp[i];
            acc += bf2f((unsigned short)(r >> 16)) * bf2f(feat[(r & 0xFFFF) * DD + lane]);
        }
    }

    float dm = (float)(deg > 1u ? deg : 1u);
    aggb[(size_t)node * DD + lane] = f2bf(acc / dm);
}

// ---------------------------------------------------------------------------
// out[n][j] = relu( b[j] + X[n][:]·W[j][0:64] + A[n][:]·W[j][64:128] )
// X, A are bf16; W^T staged in LDS; 4x4 fp32 micro-tile per thread.
// Emits fp32 (out) and/or bf16 (outb).
// ---------------------------------------------------------------------------
__global__ __launch_bounds__(256) void sage_gemm_relu(
    const ushort* __restrict__ X, const ushort* __restrict__ A,
    const float* __restrict__ W, const float* __restrict__ bias,
    float* __restrict__ out, ushort* __restrict__ outb)
{
    __shared__ float Ws[128 * WS_STRIDE];
    int tid = threadIdx.x;
    int nb = blockIdx.x * 64;

    for (int idx = tid; idx < 8192; idx += 256) {
        int j = idx >> 7;
        int k = idx & 127;
        Ws[k * WS_STRIDE + j] = W[idx];
    }
    __syncthreads();

    int tx = tid & 15;
    int ty = tid >> 4;

    int r[4];
#pragma unroll
    for (int i = 0; i < 4; ++i) {
        int row = nb + ty * 4 + i;
        r[i] = row < NN ? row : NN - 1;
    }

    float acc[4][4];
#pragma unroll
    for (int i = 0; i < 4; ++i)
#pragma unroll
        for (int j = 0; j < 4; ++j) acc[i][j] = 0.f;

#pragma unroll 4
    for (int k4 = 0; k4 < 16; ++k4) {
        float4 a[4], w[4];
#pragma unroll
        for (int i = 0; i < 4; ++i) {
            ushort4 u = *(const ushort4*)&X[r[i] * 64 + k4 * 4];
            a[i] = make_float4(bf2f(u.x), bf2f(u.y), bf2f(u.z), bf2f(u.w));
        }
#pragma unroll
        for (int kk = 0; kk < 4; ++kk)
            w[kk] = *(const float4*)&Ws[(k4 * 4 + kk) * WS_STRIDE + tx * 4];
#pragma unroll
        for (int i = 0; i < 4; ++i) {
            acc[i][0] += a[i].x * w[0].x + a[i].y * w[1].x + a[i].z * w[2].x + a[i].w * w[3].x;
            acc[i][1] += a[i].x * w[0].y + a[i].y * w[1].y + a[i].z * w[2].y + a[i].w * w[3].y;
            acc[i][2] += a[i].x * w[0].z + a[i].y * w[1].z + a[i].z * w[2].z + a[i].w * w[3].z;
            acc[i][3] += a[i].x * w[0].w + a[i].y * w[1].w + a[i].z * w[2].w + a[i].w * w[3].w;
        }
    }
#pragma unroll 4
    for (int k4 = 0; k4 < 16; ++k4) {
        float4 a[4], w[4];
#pragma unroll
        for (int i = 0; i < 4; ++i) {
            ushort4 u = *(const ushort4*)&A[r[i] * 64 + k4 * 4];
            a[i] = make_float4(bf2f(u.x), bf2f(u.y), bf2f(u.z), bf2f(u.w));
        }
#pragma unroll
        for (int kk = 0; kk < 4; ++kk)
            w[kk] = *(const float4*)&Ws[(64 + k4 * 4 + kk) * WS_STRIDE + tx * 4];
#pragma unroll
        for (int i = 0; i < 4; ++i) {
            acc[i][0] += a[i].x * w[0].x + a[i].y * w[1].x + a[i].z * w[2].x + a[i].w * w[3].x;
            acc[i][1] += a[i].x * w[0].y + a[i].y * w[1].y + a[i].z * w[2].y + a[i].w * w[3].y;
            acc[i][2] += a[i].x * w[0].z + a[i].y * w[1].z + a[i].z * w[2].z + a[i].w * w[3].z;
            acc[i][3] += a[i].x * w[0].w + a[i].y * w[1].w + a[i].z * w[2].w + a[i].w * w[3].w;
        }
    }

    float4 bb = *(const float4*)&bias[tx * 4];
#pragma unroll
    for (int i = 0; i < 4; ++i) {
        int n = nb + ty * 4 + i;
        if (n < NN) {
            float4 o;
            o.x = fmaxf(acc[i][0] + bb.x, 0.f);
            o.y = fmaxf(acc[i][1] + bb.y, 0.f);
            o.z = fmaxf(acc[i][2] + bb.z, 0.f);
            o.w = fmaxf(acc[i][3] + bb.w, 0.f);
            if (out) *(float4*)&out[n * 64 + tx * 4] = o;
            if (outb) {
                ushort4 ob;
                ob.x = f2bf(o.x); ob.y = f2bf(o.y); ob.z = f2bf(o.z); ob.w = f2bf(o.w);
                *(ushort4*)&outb[n * 64 + tx * 4] = ob;
            }
        }
    }
}

// ---------------------------------------------------------------------------
extern "C" void kernel_launch(void* const* d_in, const int* in_sizes, int n_in,
                              void* d_out, int out_size, void* d_ws, size_t ws_size,
                              hipStream_t stream)
{
    const float* x  = (const float*)d_in[0];
    const int*   ei = (const int*)d_in[1];
    const float* ew = (const float*)d_in[2];
    const float* W1 = (const float*)d_in[3];
    const float* b1 = (const float*)d_in[4];
    const float* W2 = (const float*)d_in[5];
    const float* b2 = (const float*)d_in[6];
    float* out = (float*)d_out;

    // workspace layout, 50.4 MB total (16B-aligned offsets)
    char* ws = (char*)d_ws;
    int*          cnt  = (int*)ws;                          //  2,400,000 B (NN*12*4)
    unsigned int* bbuf = (unsigned int*)(ws + 2400000);     // 28,800,000 B (NN*9*16*4)
    ushort*       xb   = (ushort*)(ws + 31200000);          //  6,400,000 B
    ushort*       aggb = (ushort*)(ws + 37600000);          //  6,400,000 B
    ushort*       h1b  = (ushort*)(ws + 44000000);          //  6,400,000 B

    hipMemsetAsync(cnt, 0, NN * CSTR * sizeof(int), stream);

    cast_bf16<<<(NN * DD / 4) / 256, 256, 0, stream>>>(x, xb, NN * DD / 4);
    build_slots<<<NE / 256, 256, 0, stream>>>(ei, ew, cnt, bbuf);

    // layer 1
    aggregate<<<(NN * 64) / 256, 256, 0, stream>>>(xb, cnt, bbuf, aggb);
    sage_gemm_relu<<<(NN + 63) / 64, 256, 0, stream>>>(xb, aggb, W1, b1, nullptr, h1b);

    // layer 2 (same graph, reuse slots)
    aggregate<<<(NN * 64) / 256, 256, 0, stream>>>(h1b, cnt, bbuf, aggb);
    sage_gemm_relu<<<(NN + 63) / 64, 256, 0, stream>>>(h1b, aggb, W2, b2, out, nullptr);
}